// Round 15
// baseline (114.846 us; speedup 1.0000x reference)
//
#include <hip/hip_runtime.h>
#include <hip/hip_bf16.h>

#define N_ROWS 8192
#define DIM 256
#define NANCH 64
#define NVIEW 128
#define NPART 8     // column partitions (8 anchors = 1024 cols each)

typedef __attribute__((ext_vector_type(8))) short bf16x8;
typedef __attribute__((ext_vector_type(16))) float f32x16;
typedef __attribute__((ext_vector_type(4))) float float4v;
typedef __attribute__((ext_vector_type(4))) unsigned short ushort4v;

__device__ __forceinline__ unsigned short f2bf(float x) {
  union { float f; unsigned int u; } c; c.f = x;
  unsigned int u = c.u;
  unsigned int r = (u + 0x7fffu + ((u >> 16) & 1u)) >> 16;
  return (unsigned short)r;
}

__device__ __forceinline__ float bf2f(unsigned short b) {
  union { unsigned int u; float f; } c; c.u = ((unsigned int)b) << 16;
  return c.f;
}

__device__ __forceinline__ void gload_lds16(const void* g, void* l) {
  __builtin_amdgcn_global_load_lds(
      (const __attribute__((address_space(1))) unsigned int*)g,
      (__attribute__((address_space(3))) unsigned int*)l, 16, 0, 0);
}

// fp32 -> bf16 (1/sqrt(T) prescale) into FRAGMENT-LINEAR layout + row norms.
// Layout (validated R14): colblk cb = row>>5, ks = k>>4 -> 1 KB fragment at
// (cb*16+ks)*1024, cell (khalf*32 + row&31)*16B. Every MFMA fragment load
// (A, B, or LDS stage) is then a fully-coalesced contiguous access.
__global__ void cast_diag_kernel(const float4v* __restrict__ in,
                                 char* __restrict__ Xf,
                                 float* __restrict__ diag) {
  const int w = threadIdx.x >> 6;
  const int l = threadIdx.x & 63;
  const int row = blockIdx.x * 4 + w;
  const float s = 3.16227766016838f; // 1/sqrt(0.1)
  float4v v = in[row * 64 + l];
  ushort4v o;
  o.x = f2bf(v.x * s);
  o.y = f2bf(v.y * s);
  o.z = f2bf(v.z * s);
  o.w = f2bf(v.w * s);
  const size_t off = ((size_t)((row >> 5) * 16 + (l >> 2))) * 1024 +
                     ((l >> 1) & 1) * 512 + (row & 31) * 16 + (l & 1) * 8;
  *(ushort4v*)(Xf + off) = o;
  float c0 = bf2f(o.x), c1 = bf2f(o.y), c2 = bf2f(o.z), c3 = bf2f(o.w);
  float ss = c0 * c0 + c1 * c1 + c2 * c2 + c3 * c3;
#pragma unroll
  for (int st = 1; st < 64; st <<= 1) ss += __shfl_xor(ss, st);
  if (l == 0) diag[row] = ss;
}

// -------- Kernel 2: fused pass over (256 rows x 1024 cols) per block.
// R8's PROVEN schedule (ring-4 LDS staged 3-deep, counted vmcnt 12/8/4/0,
// raw s_barrier pairs, setprio MFMA cluster) + R14's fragment-linear layout
// (staging is now a COALESCED linear 32 KB copy -- R8's staging had 512B
// lane stride = 64 cache lines per instruction) + the R9-14 verified fused
// epilogue (no separate positives kernel). grid = 32 rb x 8 parts = 256
// blocks (1/CU); 512 thr = 8 waves (4 row-groups x 2 col-groups).
//   NEG anchors -> ns += exp(v - diag)   [underflow-skipped]
//   POS anchors -> sd += (v - diag); ep += exp(v - diag) [diag masked]
__global__ __launch_bounds__(512, 2) void pcl_negsum(
    const char* __restrict__ Xf, const int* __restrict__ labels,
    const float* __restrict__ diag, float* __restrict__ ns_partial,
    float* __restrict__ sd_partial, float* __restrict__ ep_partial) {
  const int bx = blockIdx.x;
  const int part = bx & 7;            // same part -> same XCD (L2 panel reuse)
  const int rb = bx >> 3;             // rows rb*256 .. +255
  const int abase = part * 8;         // 8 col-anchors = 1024 cols
  const int tid = threadIdx.x;        // 0..511
  const int wid = tid >> 6;           // 0..7
  const int lane = tid & 63;
  const int l31 = lane & 31;
  const int khalf = lane >> 5;
  const int rg = wid >> 1;            // row group (64 rows)
  const int cg = wid & 1;             // col group (32 cols = 1 colblk)
  const int R0 = rb * 256;

  __shared__ __align__(16) char ring[4 * 32768];  // 4-slot B-tile ring, 128 KB
  __shared__ float sdiag[256];
  __shared__ float nsacc[256];
  __shared__ float sdacc[256];
  __shared__ float epacc[256];
  __shared__ int slab[NANCH];

  if (tid < NANCH) slab[tid] = labels[tid];
  if (tid < 256) {
    sdiag[tid] = diag[R0 + tid];
    nsacc[tid] = 0.f;
    sdacc[tid] = 0.f;
    epacc[tid] = 0.f;
  }
  __syncthreads();
  const int myAnch = rb * 2 + (rg >> 1);  // wave's 64 rows lie in this anchor
  const int myLab = slab[myAnch];

  // A fragments: colblk = rb*8 + rg*2 + ri; one coalesced 1 KB load each.
  bf16x8 afrag[2][16];
#pragma unroll
  for (int ri = 0; ri < 2; ++ri) {
#pragma unroll
    for (int ks = 0; ks < 16; ++ks) {
      const char* p = Xf +
          ((size_t)((rb * 8 + rg * 2 + ri) * 16 + ks)) * 1024 + lane * 16;
      afrag[ri][ks] = *(const bf16x8*)p;
    }
  }
#pragma unroll
  for (int ri = 0; ri < 2; ++ri)
#pragma unroll
    for (int ks = 0; ks < 16; ++ks) asm volatile("" : "+v"(afrag[ri][ks]));
  // Drain A loads so the counted-vmcnt bookkeeping below is exact.
  asm volatile("s_waitcnt vmcnt(0)");

  // Wave-uniform skip threshold: min diag over this wave's 64 rows - 40.
  float thr;
  {
    float d = sdiag[rg * 64 + lane];
#pragma unroll
    for (int st = 1; st < 64; st <<= 1) d = fminf(d, __shfl_xor(d, st));
    thr = d - 40.f;
  }

  char* const L0 = &ring[0];
  // B tile T (0..15) = colblks part*32 + T*2 + {0,1} = 32 KB CONTIGUOUS in Xf.
  const char* const Bpanel = Xf + (size_t)(part * 32) * 16384;

  // Linear coalesced stage: thread covers bytes (tid + i*512)*16, i=0..3.
#define STAGE(T)                                                                \
  do {                                                                          \
    const char* _s = Bpanel + (size_t)(T) * 32768 + tid * 16;                   \
    char* _d = L0 + ((T) & 3) * 32768 + wid * 1024;                             \
    gload_lds16(_s, _d);                                                        \
    gload_lds16(_s + 8192, _d + 8192);                                          \
    gload_lds16(_s + 16384, _d + 16384);                                        \
    gload_lds16(_s + 24576, _d + 24576);                                        \
  } while (0)

#define MFMA32(A, B, C) __builtin_amdgcn_mfma_f32_32x32x16_bf16(A, B, C, 0, 0, 0)

#define BODY(T, VNSTR)                                                          \
  do {                                                                          \
    if ((T) + 3 < 16) STAGE((T) + 3);                                           \
    asm volatile("s_waitcnt vmcnt(" VNSTR ")");                                 \
    __builtin_amdgcn_sched_barrier(0);                                          \
    __builtin_amdgcn_s_barrier();                                               \
    __builtin_amdgcn_sched_barrier(0);                                          \
    const char* _sb = L0 + ((T) & 3) * 32768 + cg * 16384 + lane * 16;          \
    f32x16 c00 = {}, c01 = {}, c10 = {}, c11 = {};                              \
    __builtin_amdgcn_s_setprio(1);                                              \
    _Pragma("unroll") for (int ks = 0; ks < 8; ++ks) {                          \
      bf16x8 b0 = *(const bf16x8*)(_sb + ks * 1024);                            \
      bf16x8 b1 = *(const bf16x8*)(_sb + (ks + 8) * 1024);                      \
      c00 = MFMA32(afrag[0][ks], b0, c00);                                      \
      c10 = MFMA32(afrag[1][ks], b0, c10);                                      \
      c01 = MFMA32(afrag[0][ks + 8], b1, c01);                                  \
      c11 = MFMA32(afrag[1][ks + 8], b1, c11);                                  \
    }                                                                           \
    __builtin_amdgcn_s_setprio(0);                                              \
    /* ---- fused epilogue for tile T ---- */                                   \
    {                                                                           \
      const bool is_pos = (slab[abase + ((T) >> 1)] == myLab);                  \
      f32x16 c0 = c00 + c01;                                                    \
      f32x16 c1 = c10 + c11;                                                    \
      float vmax = fmaxf(c0[0], c1[0]);                                         \
      _Pragma("unroll") for (int r = 1; r < 16; ++r)                            \
          vmax = fmaxf(vmax, fmaxf(c0[r], c1[r]));                              \
      const bool anyhot = __any(vmax > thr);                                    \
      const int gcol = part * 1024 + (T) * 64 + cg * 32 + l31;                  \
      if (__builtin_expect(is_pos, 0)) {                                        \
        if (!anyhot) {                                                          \
          _Pragma("unroll") for (int ri = 0; ri < 2; ++ri) {                    \
            _Pragma("unroll") for (int r = 0; r < 16; ++r) {                    \
              const int rloc = (r & 3) + 8 * (r >> 2) + 4 * khalf;              \
              const int row = rg * 64 + ri * 32 + rloc;                         \
              float d = (ri ? c1[r] : c0[r]) - sdiag[row];                      \
              _Pragma("unroll") for (int st = 1; st < 32; st <<= 1)             \
                  d += __shfl_xor(d, st);                                       \
              if (l31 == 0) atomicAdd(&sdacc[row], d);                          \
            }                                                                   \
          }                                                                     \
        } else {                                                                \
          _Pragma("unroll") for (int ri = 0; ri < 2; ++ri) {                    \
            _Pragma("unroll") for (int r = 0; r < 16; ++r) {                    \
              const int rloc = (r & 3) + 8 * (r >> 2) + 4 * khalf;              \
              const int row = rg * 64 + ri * 32 + rloc;                         \
              const bool isdiag = (R0 + row) == gcol;                           \
              float v = (ri ? c1[r] : c0[r]);                                   \
              float d = v - sdiag[row];                                         \
              float sd_e = isdiag ? 0.f : d;                                    \
              float e = (!isdiag && d > -40.f) ? __expf(d) : 0.f;               \
              _Pragma("unroll") for (int st = 1; st < 32; st <<= 1) {           \
                sd_e += __shfl_xor(sd_e, st);                                   \
                e += __shfl_xor(e, st);                                         \
              }                                                                 \
              if (l31 == 0) {                                                   \
                atomicAdd(&sdacc[row], sd_e);                                   \
                if (e != 0.f) atomicAdd(&epacc[row], e);                        \
              }                                                                 \
            }                                                                   \
          }                                                                     \
        }                                                                       \
      } else if (__builtin_expect(anyhot, 0)) {                                 \
        _Pragma("unroll") for (int ri = 0; ri < 2; ++ri) {                      \
          _Pragma("unroll") for (int r = 0; r < 16; ++r) {                      \
            const int rloc = (r & 3) + 8 * (r >> 2) + 4 * khalf;                \
            const int row = rg * 64 + ri * 32 + rloc;                           \
            float d = (ri ? c1[r] : c0[r]) - sdiag[row];                        \
            float e = (d > -40.f) ? __expf(d) : 0.f;                            \
            _Pragma("unroll") for (int st = 1; st < 32; st <<= 1)               \
                e += __shfl_xor(e, st);                                         \
            if (l31 == 0) atomicAdd(&nsacc[row], e);                            \
          }                                                                     \
        }                                                                       \
      }                                                                         \
    }                                                                           \
    __builtin_amdgcn_s_barrier();                                               \
  } while (0)

  // prologue: stage tiles 0..2 (3-deep)
  STAGE(0);
  STAGE(1);
  STAGE(2);

  BODY(0, "12");  BODY(1, "12");  BODY(2, "12");  BODY(3, "12");
  BODY(4, "12");  BODY(5, "12");  BODY(6, "12");  BODY(7, "12");
  BODY(8, "12");  BODY(9, "12");  BODY(10, "12"); BODY(11, "12");
  BODY(12, "12"); BODY(13, "8");  BODY(14, "4");  BODY(15, "0");

#undef BODY
#undef MFMA32
#undef STAGE

  __syncthreads();
  if (tid < 256) {
    ns_partial[part * N_ROWS + R0 + tid] = nsacc[tid];
    sd_partial[part * N_ROWS + R0 + tid] = sdacc[tid];
    ep_partial[part * N_ROWS + R0 + tid] = epacc[tid];
  }
}

// -------- Kernel 3: per-row combine. 32 blocks x 256 threads, 1 row/thread.
// mean_log_prob_pos = (SD - npos*log(NS+eps) - EP/(NS+eps)) / npos
__global__ void pcl_combine(const int* __restrict__ labels,
                            const float* __restrict__ ns_partial,
                            const float* __restrict__ sd_partial,
                            const float* __restrict__ ep_partial,
                            float* __restrict__ partials) {
  const int tid = threadIdx.x;
  const int row = blockIdx.x * 256 + tid;
  __shared__ int slab[NANCH];
  __shared__ float sred[256];
  if (tid < NANCH) slab[tid] = labels[tid];
  __syncthreads();

  const int lab = slab[row >> 7];
  int cnt = 0;
#pragma unroll
  for (int b = 0; b < NANCH; ++b) cnt += (slab[b] == lab) ? 1 : 0;

  float NS = 0.f, SD = 0.f, EP = 0.f;
#pragma unroll
  for (int p = 0; p < NPART; ++p) {
    NS += ns_partial[p * N_ROWS + row];
    SD += sd_partial[p * N_ROWS + row];
    EP += ep_partial[p * N_ROWS + row];
  }
  const float npos = (float)(cnt * NVIEW - 1);
  const float nse = NS + 1e-10f;
  const float mlpp = (SD - npos * __logf(nse) - EP / nse) / npos;
  sred[tid] = mlpp;
  __syncthreads();
  for (int st = 128; st > 0; st >>= 1) {
    if (tid < st) sred[tid] += sred[tid + st];
    __syncthreads();
  }
  if (tid == 0) partials[blockIdx.x] = sred[0];
}

__global__ void final_reduce(const float* __restrict__ partials, float* __restrict__ out) {
  __shared__ float s[32];
  int t = threadIdx.x;
  if (t < 32) s[t] = partials[t];
  __syncthreads();
  if (t == 0) {
    float sum = 0.f;
    for (int r = 0; r < 32; ++r) sum += s[r];
    out[0] = -(0.1f / 0.07f) * sum / (float)N_ROWS;
  }
}

extern "C" void kernel_launch(void* const* d_in, const int* in_sizes, int n_in,
                              void* d_out, int out_size, void* d_ws, size_t ws_size,
                              hipStream_t stream) {
  const float* feats = (const float*)d_in[0];
  const int* labels = (const int*)d_in[1];
  float* out = (float*)d_out;

  char* base = (char*)d_ws;
  char* Xf = (char*)d_ws;                                          // 4 MB
  size_t off = (size_t)N_ROWS * DIM * 2;
  float* diag = (float*)(base + off);       off += N_ROWS * 4;     // 32 KB
  float* ns_partial = (float*)(base + off); off += (size_t)NPART * N_ROWS * 4;
  float* sd_partial = (float*)(base + off); off += (size_t)NPART * N_ROWS * 4;
  float* ep_partial = (float*)(base + off); off += (size_t)NPART * N_ROWS * 4;
  float* partials = (float*)(base + off);

  cast_diag_kernel<<<N_ROWS / 4, 256, 0, stream>>>((const float4v*)feats,
                                                   Xf, diag);
  pcl_negsum<<<32 * NPART, 512, 0, stream>>>(Xf, labels, diag, ns_partial,
                                             sd_partial, ep_partial);
  pcl_combine<<<N_ROWS / 256, 256, 0, stream>>>(labels, ns_partial, sd_partial,
                                                ep_partial, partials);
  final_reduce<<<1, 64, 0, stream>>>(partials, out);
}